// Round 4
// baseline (468.791 us; speedup 1.0000x reference)
//
#include <hip/hip_runtime.h>
#include <hip/hip_bf16.h>

#define NSITES 100000
#define KOFFS 27
#define CIN 64
#define COUT 128

typedef unsigned short u16;
typedef __attribute__((ext_vector_type(8))) short s16x8;
typedef __attribute__((ext_vector_type(4))) float f32x4;

static __device__ __forceinline__ u16 f2bf(float f) {
    union { float f; unsigned u; } x; x.f = f;
    return (u16)((x.u + 0x7FFFu + ((x.u >> 16) & 1u)) >> 16);
}
static __device__ __forceinline__ float bf2f(u16 v) {
    union { unsigned u; float f; } x; x.u = ((unsigned)v) << 16;
    return x.f;
}

// Barrier with LDS-visibility only: drains ds-writes (lgkmcnt), leaves global
// loads (gather/B prefetch) in flight. __syncthreads would drain vmcnt(0).
static __device__ __forceinline__ void lds_barrier() {
    asm volatile("s_waitcnt lgkmcnt(0)" ::: "memory");
    __builtin_amdgcn_s_barrier();
    __builtin_amdgcn_sched_barrier(0);  // no hoisting of LDS ops across the barrier
}

// ---------- prep: transpose/convert weights to bf16 [k][d][c], zero stat partials ----------
__global__ void prep_kernel(const float* __restrict__ W1, const float* __restrict__ W2,
                            const float* __restrict__ Wsk,
                            u16* __restrict__ W1t, u16* __restrict__ W2t,
                            u16* __restrict__ Wskt, float* __restrict__ zero_area) {
    int i = blockIdx.x * 256 + threadIdx.x;
    if (i < 27 * 64 * 128) {
        int k = i / 8192, r = i & 8191, d = r >> 6, c = r & 63;
        W1t[i] = f2bf(W1[k * 8192 + c * 128 + d]);
        return;
    }
    i -= 27 * 64 * 128;
    if (i < 27 * 128 * 128) {
        int k = i / 16384, r = i & 16383, d = r >> 7, c = r & 127;
        W2t[i] = f2bf(W2[k * 16384 + c * 128 + d]);
        return;
    }
    i -= 27 * 128 * 128;
    if (i < 8192) {
        int d = i >> 6, c = i & 63;
        Wskt[i] = f2bf(Wsk[c * 128 + d]);
        return;
    }
    i -= 8192;
    zero_area[i] = 0.0f;  // 4 * 64*128 partial-stat floats
}

// ---------- x (fp32) -> bf16 rows, plus zero sentinel row N ----------
__global__ void convert_x_kernel(const float* __restrict__ x, u16* __restrict__ xb) {
    long long e = ((long long)blockIdx.x * 256 + threadIdx.x) * 8;
    if (e >= (long long)(NSITES + 1) * CIN) return;
    s16x8 o;
    if (e < (long long)NSITES * CIN) {
        float4 v0 = *(const float4*)(x + e);
        float4 v1 = *(const float4*)(x + e + 4);
        o[0] = (short)f2bf(v0.x); o[1] = (short)f2bf(v0.y);
        o[2] = (short)f2bf(v0.z); o[3] = (short)f2bf(v0.w);
        o[4] = (short)f2bf(v1.x); o[5] = (short)f2bf(v1.y);
        o[6] = (short)f2bf(v1.z); o[7] = (short)f2bf(v1.w);
    } else {
#pragma unroll
        for (int j = 0; j < 8; ++j) o[j] = 0;
    }
    *(s16x8*)(xb + e) = o;
}

// ---------- gather-GEMM conv: round-3 pipeline + L2-pollution fixes ----------
// y[n0+r, :] = sum_k f(xin[nbr[r,k]]) @ Wt[k]^T ; Wt layout [27][COUT][CK] bf16.
// f = identity (conv1) or fused BN1-affine+ReLU applied at stage time (conv2,
// TRANSFORM=true: staging thread always handles channels [schunk*8, +8) so the
// 8 a/b coefficients live in registers; sentinel neighbors staged as zero).
// All y/identity stores are NONTEMPORAL: the stores were cycling the entire
// 4 MB per-XCD L2 (conv1: 77 MB of write-allocate per dispatch) and evicting
// the gather table between reuses — conv1's measured 13% gather hit rate vs
// conv2's 54% on a table HALF the size is the smoking gun. The miss path is
// byte-saturated (~1.47 TB/s, schedule-invariant over rounds 0-3), so fewer
// miss bytes is the only lever left.
template <int CK, bool IDENT_FUSE, bool STATS, bool TRANSFORM>
__global__ __launch_bounds__(256, 3) void conv_kernel(
    const u16* __restrict__ xin, const int* __restrict__ nbr,
    const u16* __restrict__ Wt, u16* __restrict__ yout,
    float* __restrict__ psum, float* __restrict__ psq, int nk_unused,
    const u16* __restrict__ Wskt, float* __restrict__ outid,
    const float* __restrict__ abst) {
    constexpr int STRIDE = CK + 4;   // +4 bf16 pad
    constexpr int KSTEPS = CK / 32;
    constexpr int CPR = CK / 8;      // 16B chunks per row
    constexpr int RPP = 256 / CPR;   // rows staged per pass
    constexpr int NPASS = 64 / RPP;
    __shared__ __align__(16) u16 a_tile[2][64 * STRIDE];
    __shared__ int nbr_tile[64 * KOFFS];

    const int tid = threadIdx.x;
    const int wave = tid >> 6;
    const int lane = tid & 63;
    const int m = lane & 15;
    const int q = lane >> 4;
    const int n0 = blockIdx.x * 64;
    const int wc = wave * 32;
    const int srow = tid / CPR;
    const int schunk = tid % CPR;

    // stage-transform coefficients: channels are per-thread constant
    float a8[8], b8[8];
    if constexpr (TRANSFORM) {
        const int cb = schunk * 8;
#pragma unroll
        for (int j = 0; j < 8; ++j) {
            a8[j] = abst[cb + j];
            b8[j] = abst[COUT + cb + j];
        }
    }

    for (int i = tid; i < 64 * KOFFS; i += 256) {
        int r = i / KOFFS;
        int kk = i - r * KOFFS;
        int row = n0 + r;
        nbr_tile[i] = (row < NSITES) ? __builtin_nontemporal_load(&nbr[row * KOFFS + kk])
                                     : NSITES;
    }
    __syncthreads();  // nbr_tile ready; clean vmcnt slate

    f32x4 acc[4][2];
#pragma unroll
    for (int rt = 0; rt < 4; ++rt)
#pragma unroll
        for (int ct = 0; ct < 2; ++ct)
#pragma unroll
            for (int r = 0; r < 4; ++r) acc[rt][ct][r] = 0.0f;

    s16x8 gA[NPASS], gB[NPASS];          // gather register sets (A-rows)
    int   sA[NPASS], sB[NPASS];          // sentinel flags (TRANSFORM only)
    s16x8 bA[2][KSTEPS], bB[2][KSTEPS];  // B fragment sets

    auto gload = [&](s16x8 (&g)[NPASS], int (&sen)[NPASS], int kk) {
#pragma unroll
        for (int p = 0; p < NPASS; ++p) {
            int r = p * RPP + srow;
            int idx = nbr_tile[r * KOFFS + kk];
            long long gi;
            if constexpr (TRANSFORM) {
                sen[p] = (idx == NSITES);
                gi = sen[p] ? 0 : idx;  // clamp: xin (=y) has no sentinel row
            } else {
                gi = idx;               // xin (=xb) has a real zero row at NSITES
            }
            g[p] = *(const s16x8*)(xin + gi * CK + schunk * 8);
        }
    };
    auto bload = [&](s16x8 (&b)[2][KSTEPS], int kk) {
        const u16* wb = Wt + (long long)kk * (COUT * CK);
#pragma unroll
        for (int ct = 0; ct < 2; ++ct)
#pragma unroll
            for (int ks = 0; ks < KSTEPS; ++ks)
                b[ct][ks] = *(const s16x8*)(wb + (wc + ct * 16 + m) * CK + ks * 32 + q * 8);
    };
    auto awrite = [&](s16x8 (&g)[NPASS], int (&sen)[NPASS], int buf) {
#pragma unroll
        for (int p = 0; p < NPASS; ++p) {
            s16x8 o;
            if constexpr (TRANSFORM) {
#pragma unroll
                for (int j = 0; j < 8; ++j) {
                    float v = bf2f((u16)g[p][j]);
                    v = fmaxf(v * a8[j] + b8[j], 0.f);
                    o[j] = sen[p] ? (short)0 : (short)f2bf(v);
                }
            } else {
                o = g[p];
            }
            *(s16x8*)(&a_tile[buf][(p * RPP + srow) * STRIDE + schunk * 8]) = o;
        }
    };
    auto mfma_from = [&](int buf, s16x8 (&b)[2][KSTEPS]) {
        __builtin_amdgcn_s_setprio(1);
#pragma unroll
        for (int ks = 0; ks < KSTEPS; ++ks) {
            s16x8 af[4];
#pragma unroll
            for (int rt = 0; rt < 4; ++rt)
                af[rt] = *(const s16x8*)(&a_tile[buf][(rt * 16 + m) * STRIDE + ks * 32 + q * 8]);
#pragma unroll
            for (int rt = 0; rt < 4; ++rt)
#pragma unroll
                for (int ct = 0; ct < 2; ++ct)
                    acc[rt][ct] = __builtin_amdgcn_mfma_f32_16x16x32_bf16(
                        af[rt], b[ct][ks], acc[rt][ct], 0, 0, 0);
        }
        __builtin_amdgcn_s_setprio(0);
    };

    // prologue — ordering invariant: each B_j issued before G_{j+1}
    gload(gA, sA, 0);  // G_0
    bload(bA, 0);      // B_0  (older than G_1)
    awrite(gA, sA, 0); // stage A_0 (wait covers only G_0; B_0 stays in flight)
    gload(gA, sA, 1);  // G_1
    bload(bB, 1);      // B_1  (older than G_2)
    gload(gB, sB, 2);  // G_2
    lds_barrier();     // buf0 visible

    auto conv_iter = [&](int k, s16x8 (&g)[NPASS], int (&sen)[NPASS],
                         s16x8 (&bcur)[2][KSTEPS]) {
        awrite(g, sen, (k + 1) & 1);
        gload(g, sen, k + 3);
        lds_barrier();            // A_{k+1} staged
        mfma_from(k & 1, bcur);
        bload(bcur, k + 2);       // refill for iter k+2 (ordering invariant holds)
        lds_barrier();            // MFMA reads done before next awrite
    };

    // branch-free main loop: k = 0..23 (k+3 <= 26 always in range)
    for (int k = 0; k < 24; k += 2) {
        conv_iter(k, gA, sA, bA);
        conv_iter(k + 1, gB, sB, bB);
    }
    // peeled tail k = 24, 25, 26 (KOFFS = 27)
    awrite(gA, sA, 1);             // A_25
    lds_barrier();
    mfma_from(0, bA);              // B_24
    bload(bA, 26);                 // B_26 for iter 26
    lds_barrier();
    awrite(gB, sB, 0);             // A_26
    lds_barrier();
    mfma_from(1, bB);              // B_25
    lds_barrier();
    mfma_from(0, bA);              // B_26

    // Store y (bf16, NONTEMPORAL): C/D layout col=lane&15, row=(lane>>4)*4+reg
#pragma unroll
    for (int rt = 0; rt < 4; ++rt) {
        int rowb = n0 + rt * 16 + q * 4;
#pragma unroll
        for (int ct = 0; ct < 2; ++ct) {
            int col = wc + ct * 16 + m;
#pragma unroll
            for (int r = 0; r < 4; ++r) {
                int row = rowb + r;
                if (row < NSITES)
                    __builtin_nontemporal_store((short)f2bf(acc[rt][ct][r]),
                                                (short*)yout + (long long)row * COUT + col);
            }
        }
    }

    if (STATS) {
#pragma unroll
        for (int ct = 0; ct < 2; ++ct) {
            float s = 0.f, ss = 0.f;
#pragma unroll
            for (int rt = 0; rt < 4; ++rt)
#pragma unroll
                for (int r = 0; r < 4; ++r) {
                    float v = acc[rt][ct][r];
                    s += v; ss += v * v;
                }
            s += __shfl_xor(s, 16); ss += __shfl_xor(ss, 16);
            s += __shfl_xor(s, 32); ss += __shfl_xor(ss, 32);
            if (q == 0) {
                int col = wc + ct * 16 + m;
                int slot = blockIdx.x & 63;  // 64-slot tree cuts atomic contention
                atomicAdd(psum + slot * COUT + col, s);
                atomicAdd(psq + slot * COUT + col, ss);
            }
        }
    }

    if (IDENT_FUSE) {
        // identity = x @ W_skip for the same 64 rows (no gather); reuses acc regs
        lds_barrier();  // last MFMA's reads of a_tile[0] done before restaging
#pragma unroll
        for (int rt = 0; rt < 4; ++rt)
#pragma unroll
            for (int ct = 0; ct < 2; ++ct)
#pragma unroll
                for (int r = 0; r < 4; ++r) acc[rt][ct][r] = 0.0f;
        s16x8 aid[NPASS];
#pragma unroll
        for (int p = 0; p < NPASS; ++p) {
            int row = n0 + p * RPP + srow;
            long long idx = (row < NSITES) ? row : NSITES;
            aid[p] = *(const s16x8*)(xin + idx * CK + schunk * 8);
        }
        s16x8 bfi[2][KSTEPS];
#pragma unroll
        for (int ct = 0; ct < 2; ++ct)
#pragma unroll
            for (int ks = 0; ks < KSTEPS; ++ks)
                bfi[ct][ks] = *(const s16x8*)(Wskt + (wc + ct * 16 + m) * CK + ks * 32 + q * 8);
        int sdum[NPASS];
#pragma unroll
        for (int p = 0; p < NPASS; ++p) sdum[p] = 0;
        awrite(aid, sdum, 0);
        lds_barrier();
        mfma_from(0, bfi);
        // identity stores f32 NONTEMPORAL into d_out (final_kernel adds on top)
#pragma unroll
        for (int rt = 0; rt < 4; ++rt) {
            int rowb = n0 + rt * 16 + q * 4;
#pragma unroll
            for (int ct = 0; ct < 2; ++ct) {
                int col = wc + ct * 16 + m;
#pragma unroll
                for (int r = 0; r < 4; ++r) {
                    int row = rowb + r;
                    if (row < NSITES)
                        __builtin_nontemporal_store(acc[rt][ct][r],
                                                    outid + (long long)row * COUT + col);
                }
            }
        }
    }
}

// ---------- reduce 64 slots -> per-column affine (a = gamma*rsqrt(var+eps), b = beta - mu*a) ----------
__global__ void bn_stats_kernel(const float* __restrict__ psum, const float* __restrict__ psq,
                                const float* __restrict__ gamma, const float* __restrict__ beta,
                                float* __restrict__ ab) {
    int col = threadIdx.x;  // 128 threads
    float s = 0.f, ss = 0.f;
    for (int i = 0; i < 64; ++i) { s += psum[i * COUT + col]; ss += psq[i * COUT + col]; }
    const float inv_n = 1.0f / (float)NSITES;
    float mu = s * inv_n;
    float var = ss * inv_n - mu * mu;
    float rs = rsqrtf(var + 1e-5f);
    float a = gamma[col] * rs;
    ab[col] = a;
    ab[COUT + col] = beta[col] - mu * a;
}

// ---------- out = relu(y2*a+b) + identity (identity resident in d_out); y2 is bf16 ----------
__global__ void final_kernel(const u16* __restrict__ y, const float* __restrict__ ab,
                             float* __restrict__ out) {
    long long e = ((long long)blockIdx.x * 256 + threadIdx.x) * 8;
    if (e >= (long long)NSITES * COUT) return;
    int cb = (int)(e & (COUT - 1));
    s16x8 v = __builtin_nontemporal_load((const s16x8*)(y + e));
    f32x4 i0 = __builtin_nontemporal_load((const f32x4*)(out + e));
    f32x4 i1 = __builtin_nontemporal_load((const f32x4*)(out + e + 4));
    f32x4 o0, o1;
#pragma unroll
    for (int j = 0; j < 4; ++j) {
        float r = bf2f((u16)v[j]) * ab[cb + j] + ab[COUT + cb + j];
        o0[j] = fmaxf(r, 0.f) + i0[j];
    }
#pragma unroll
    for (int j = 0; j < 4; ++j) {
        float r = bf2f((u16)v[4 + j]) * ab[cb + 4 + j] + ab[COUT + cb + 4 + j];
        o1[j] = fmaxf(r, 0.f) + i1[j];
    }
    __builtin_nontemporal_store(o0, (f32x4*)(out + e));
    __builtin_nontemporal_store(o1, (f32x4*)(out + e + 4));
}

extern "C" void kernel_launch(void* const* d_in, const int* in_sizes, int n_in,
                              void* d_out, int out_size, void* d_ws, size_t ws_size,
                              hipStream_t stream) {
    const float* x   = (const float*)d_in[0];
    const int*   nbr = (const int*)d_in[1];
    const float* W1  = (const float*)d_in[2];
    const float* g1  = (const float*)d_in[3];
    const float* b1  = (const float*)d_in[4];
    const float* W2  = (const float*)d_in[5];
    const float* g2  = (const float*)d_in[6];
    const float* b2  = (const float*)d_in[7];
    const float* Wsk = (const float*)d_in[8];
    float* out = (float*)d_out;

    // workspace layout (bytes, 16B-aligned); total ~66 MB
    char* ws = (char*)d_ws;
    u16*   xb   = (u16*)(ws);                    // (N+1)*64 bf16      = 12,800,128 B
    u16*   W1t  = (u16*)(ws + 12800128);         // 27*128*64 bf16     =    442,368 B
    u16*   W2t  = (u16*)(ws + 13242496);         // 27*128*128 bf16    =    884,736 B
    u16*   Wskt = (u16*)(ws + 14127232);         // 128*64 bf16        =     16,384 B
    u16*   y    = (u16*)(ws + 14143616);         // N*128 bf16 (conv1 out) = 25,600,000 B
    u16*   y2   = (u16*)(ws + 39743616);         // N*128 bf16 (conv2 out) = 25,600,256 B region
    float* ps1  = (float*)(ws + 65343872);       // 4 * 64*128 f32 partials
    float* pq1  = ps1 + 8192;
    float* ps2  = pq1 + 8192;
    float* pq2  = ps2 + 8192;
    float* ab1  = pq2 + 8192;                    // 2*2*128 f32 affine params
    float* ab2  = ab1 + 256;

    const int NBLK = (NSITES + 63) / 64;  // 1563

    prep_kernel<<<2752, 256, 0, stream>>>(W1, W2, Wsk, W1t, W2t, Wskt, ps1);
    convert_x_kernel<<<3126, 256, 0, stream>>>(x, xb);
    // conv1 + fused stats + fused identity (identity -> d_out, nt)
    conv_kernel<64, true, true, false><<<NBLK, 256, 0, stream>>>(
        xb, nbr, W1t, y, ps1, pq1, KOFFS, Wskt, out, nullptr);
    bn_stats_kernel<<<1, 128, 0, stream>>>(ps1, pq1, g1, b1, ab1);
    // conv2 gathers conv1's raw y; BN1-affine+ReLU fused at stage time (ab1)
    conv_kernel<128, false, true, true><<<NBLK, 256, 0, stream>>>(
        y, nbr, W2t, y2, ps2, pq2, KOFFS, nullptr, nullptr, ab1);
    bn_stats_kernel<<<1, 128, 0, stream>>>(ps2, pq2, g2, b2, ab2);
    final_kernel<<<6250, 256, 0, stream>>>(y2, ab2, out);
}